// Round 2
// baseline (247.697 us; speedup 1.0000x reference)
//
#include <hip/hip_runtime.h>
#include <hip/hip_bf16.h>

typedef __bf16 bf16x8 __attribute__((ext_vector_type(8)));
typedef float f32x4 __attribute__((ext_vector_type(4)));
typedef unsigned short ushort8 __attribute__((ext_vector_type(8)));
typedef unsigned short ushort_t;

#define AS3(p) ((__attribute__((address_space(3))) void*)(p))
#define AS1(p) ((const __attribute__((address_space(1))) void*)(p))

// Problem dims (fixed by setup_inputs)
constexpr int L = 8192;
constexpr int C = 1024;   // = H*D = inner
constexpr int T = 8;
constexpr int S = 1024;   // L / T

__device__ __forceinline__ float bf2f(ushort_t u) {
    return __uint_as_float(((unsigned)u) << 16);
}
__device__ __forceinline__ ushort_t f2bf(float f) {
    unsigned x = __float_as_uint(f);
    unsigned r = (x + 0x7fffu + ((x >> 16) & 1u)) >> 16;  // RNE
    return (ushort_t)r;
}

// ---------------- f32 -> bf16 convert (vectorized, 8 elems/thread) -------------
__global__ __launch_bounds__(256) void cvt_kernel(const float* __restrict__ in,
                                                  ushort_t* __restrict__ out, int n8) {
    int i = blockIdx.x * 256 + threadIdx.x;
    if (i >= n8) return;
    const float4* p = (const float4*)in + (long)i * 2;
    float4 a = p[0], b = p[1];
    ushort8 o;
    o[0] = f2bf(a.x); o[1] = f2bf(a.y); o[2] = f2bf(a.z); o[3] = f2bf(a.w);
    o[4] = f2bf(b.x); o[5] = f2bf(b.y); o[6] = f2bf(b.z); o[7] = f2bf(b.w);
    ((ushort8*)out)[i] = o;
}

// ---------------- W [K][N] f32  ->  Wt [N][K] bf16 (4 matrices via grid.z) -----
__global__ __launch_bounds__(256) void transpose4_kernel(
    const float* __restrict__ w0, const float* __restrict__ w1,
    const float* __restrict__ w2, const float* __restrict__ w3,
    ushort_t* __restrict__ o0, ushort_t* __restrict__ o1,
    ushort_t* __restrict__ o2, ushort_t* __restrict__ o3) {
    int z = blockIdx.z;
    const float* W = z == 0 ? w0 : z == 1 ? w1 : z == 2 ? w2 : w3;
    ushort_t* O    = z == 0 ? o0 : z == 1 ? o1 : z == 2 ? o2 : o3;
    __shared__ float tile[32][33];
    int tx = threadIdx.x & 31, ty = threadIdx.x >> 5;
    int bx = blockIdx.x * 32, by = blockIdx.y * 32;
#pragma unroll
    for (int i = 0; i < 32; i += 8)
        tile[ty + i][tx] = W[(long)(by + ty + i) * C + bx + tx];
    __syncthreads();
#pragma unroll
    for (int i = 0; i < 32; i += 8)
        O[(long)(bx + ty + i) * C + by + tx] = f2bf(tile[tx][ty + i]);
}

// ---------------- GEMM: A[M,K] bf16 row-major  x  Bt[N,K] bf16 row-major -------
// m97 structure: 128x128 tile, BK=32, 4 waves each 64x64 (4x4 of 16x16x32 MFMA),
// global_load_lds width-16 staging.
template <bool BF16_OUT>
__device__ __forceinline__ void gemm_body(const ushort_t* __restrict__ A,
                                          const ushort_t* __restrict__ Bt,
                                          const float* __restrict__ bias,
                                          void* __restrict__ Cv,
                                          int M, int N, int K, int bx, int by) {
    __shared__ ushort_t As[128 * 32];
    __shared__ ushort_t Bs[128 * 32];

    const int tid = threadIdx.x;
    const int wave = tid >> 6, lane = tid & 63;
    const int wr = wave >> 1, wc = wave & 1;
    const int bm0 = bx * 128, bn0 = by * 128;

    f32x4 acc[4][4] = {};

    // staging: 512 chunks of 16B per tile; chunk ci -> row=ci>>2, col=(ci&3)*8
    const int ci0 = tid, ci1 = tid + 256;
    const char* Ab = (const char*)A;
    const char* Bb = (const char*)Bt;
    const long aoff0 = ((long)(bm0 + (ci0 >> 2)) * K + (ci0 & 3) * 8) * 2;
    const long aoff1 = ((long)(bm0 + (ci1 >> 2)) * K + (ci1 & 3) * 8) * 2;
    const long boff0 = ((long)(bn0 + (ci0 >> 2)) * K + (ci0 & 3) * 8) * 2;
    const long boff1 = ((long)(bn0 + (ci1 >> 2)) * K + (ci1 & 3) * 8) * 2;
    char* ldsA = (char*)As;
    char* ldsB = (char*)Bs;
    const unsigned l0 = wave * 1024u;          // issue 0 LDS base (bytes)
    const unsigned l1 = 4096u + wave * 1024u;  // issue 1 LDS base

    const int k0 = (lane >> 4) * 8;
    const int ra = wr * 64 + (lane & 15);
    const int cbn = wc * 64 + (lane & 15);

    for (int kt = 0; kt < K; kt += 32) {
        const long kb = (long)kt * 2;
        __builtin_amdgcn_global_load_lds(AS1(Ab + aoff0 + kb), AS3(ldsA + l0), 16, 0, 0);
        __builtin_amdgcn_global_load_lds(AS1(Ab + aoff1 + kb), AS3(ldsA + l1), 16, 0, 0);
        __builtin_amdgcn_global_load_lds(AS1(Bb + boff0 + kb), AS3(ldsB + l0), 16, 0, 0);
        __builtin_amdgcn_global_load_lds(AS1(Bb + boff1 + kb), AS3(ldsB + l1), 16, 0, 0);
        __syncthreads();

        bf16x8 af[4], bfr[4];
#pragma unroll
        for (int m = 0; m < 4; m++)
            af[m] = *(const bf16x8*)(As + (ra + m * 16) * 32 + k0);
#pragma unroll
        for (int n = 0; n < 4; n++)
            bfr[n] = *(const bf16x8*)(Bs + (cbn + n * 16) * 32 + k0);
#pragma unroll
        for (int m = 0; m < 4; m++)
#pragma unroll
            for (int n = 0; n < 4; n++)
                acc[m][n] = __builtin_amdgcn_mfma_f32_16x16x32_bf16(af[m], bfr[n],
                                                                    acc[m][n], 0, 0, 0);
        __syncthreads();
    }

    // epilogue: C/D layout col=lane&15, row=(lane>>4)*4+reg
    const int r0 = bm0 + wr * 64 + (lane >> 4) * 4;
    const int c0 = bn0 + wc * 64 + (lane & 15);
#pragma unroll
    for (int n = 0; n < 4; n++) {
        const int col = c0 + n * 16;
        const float bia = bias[col];
#pragma unroll
        for (int m = 0; m < 4; m++) {
            const int row = r0 + m * 16;
#pragma unroll
            for (int r = 0; r < 4; r++) {
                float val = acc[m][n][r] + bia;
                if (BF16_OUT)
                    ((ushort_t*)Cv)[(long)(row + r) * N + col] = f2bf(val);
                else
                    ((float*)Cv)[(long)(row + r) * N + col] = val;
            }
        }
    }
}

__global__ __launch_bounds__(256) void gemm_qkv_kernel(
    const ushort_t* __restrict__ xbf,
    const ushort_t* __restrict__ WqT, const ushort_t* __restrict__ WkT,
    const ushort_t* __restrict__ WvT,
    const float* __restrict__ bq, const float* __restrict__ bk,
    const float* __restrict__ bv,
    ushort_t* __restrict__ q, ushort_t* __restrict__ k, ushort_t* __restrict__ v) {
    const int z = blockIdx.z;
    const ushort_t* Bt = z == 0 ? WqT : z == 1 ? WkT : WvT;
    const float* bias  = z == 0 ? bq : z == 1 ? bk : bv;
    ushort_t* out      = z == 0 ? q : z == 1 ? k : v;
    gemm_body<true>(xbf, Bt, bias, out, L, C, C, blockIdx.x, blockIdx.y);
}

__global__ __launch_bounds__(256) void gemm_o_kernel(
    const ushort_t* __restrict__ a, const ushort_t* __restrict__ WoT,
    const float* __restrict__ bo, float* __restrict__ outp) {
    gemm_body<false>(a, WoT, bo, outp, L, C, C, blockIdx.x, blockIdx.y);
}

// ---------------- fused RMSNorm + small-world attention ------------------------
// 1 wave per position p; lane l -> head h=l>>2, channels [l*16, l*16+16)
__global__ __launch_bounds__(256) void attn_kernel(
    const ushort_t* __restrict__ qraw, const ushort_t* __restrict__ kraw,
    const ushort_t* __restrict__ vraw,
    const float* __restrict__ qn_w, const float* __restrict__ kn_w,
    const float* __restrict__ eb, ushort_t* __restrict__ outp) {
    const int wave = threadIdx.x >> 6, lane = threadIdx.x & 63;
    const int p = blockIdx.x * 4 + wave;
    const int t = p >> 10, s = p & (S - 1);
    const int h = lane >> 2;
    const int cb = lane * 16;

    // ---- load q row, RMS over C=1024 (full-wave reduce), fold qn_w*kn_w*rstd_q
    float qf[16];
    {
        const ushort8* qp = (const ushort8*)(qraw + (long)p * C + cb);
        ushort8 a = qp[0], b = qp[1];
#pragma unroll
        for (int j = 0; j < 8; j++) { qf[j] = bf2f(a[j]); qf[8 + j] = bf2f(b[j]); }
    }
    float ss = 0.f;
#pragma unroll
    for (int j = 0; j < 16; j++) ss += qf[j] * qf[j];
#pragma unroll
    for (int m = 1; m < 64; m <<= 1) ss += __shfl_xor(ss, m);
    const float rq = rsqrtf(ss * (1.0f / C) + 1e-6f);
#pragma unroll
    for (int j = 0; j < 16; j++) qf[j] *= rq * qn_w[cb + j] * kn_w[cb + j];

    // ---- neighbor positions: 12 spatial + 4 temporal shifts
    const int SHF[16] = {1, -1, 2, -2, 4, -4, 8, -8, 16, -16, 32, -32, 1, -1, 2, -2};
    int pp[16];
#pragma unroll
    for (int n = 0; n < 16; n++) {
        if (n < 12) pp[n] = (p & ~(S - 1)) | ((s + SHF[n]) & (S - 1));
        else        pp[n] = (((t + SHF[n]) & (T - 1)) << 10) | s;
    }

    // ---- scores: per shift, k-row RMS (free wave reduce) + per-head dot
    float sc[16];
#pragma unroll
    for (int n = 0; n < 16; n++) {
        const ushort8* kp = (const ushort8*)(kraw + (long)pp[n] * C + cb);
        ushort8 a = kp[0], b = kp[1];
        float kf[16];
#pragma unroll
        for (int j = 0; j < 8; j++) { kf[j] = bf2f(a[j]); kf[8 + j] = bf2f(b[j]); }
        float ssk = 0.f, dot = 0.f;
#pragma unroll
        for (int j = 0; j < 16; j++) { ssk += kf[j] * kf[j]; dot += qf[j] * kf[j]; }
#pragma unroll
        for (int m = 1; m < 64; m <<= 1) ssk += __shfl_xor(ssk, m);
        dot += __shfl_xor(dot, 1);
        dot += __shfl_xor(dot, 2);
        const float rk = rsqrtf(ssk * (1.0f / C) + 1e-6f);
        sc[n] = dot * rk * 0.125f + eb[h * 16 + n];
    }

    // ---- softmax over 16 shifts (per lane; 4 lanes/head redundant but uniform)
    float mx = sc[0];
#pragma unroll
    for (int n = 1; n < 16; n++) mx = fmaxf(mx, sc[n]);
    float wts[16], den = 0.f;
#pragma unroll
    for (int n = 0; n < 16; n++) { wts[n] = __expf(sc[n] - mx); den += wts[n]; }
    const float inv = 1.0f / den;

    // ---- weighted V accumulation
    float o[16] = {};
#pragma unroll
    for (int n = 0; n < 16; n++) {
        const ushort8* vp = (const ushort8*)(vraw + (long)pp[n] * C + cb);
        ushort8 a = vp[0], b = vp[1];
#pragma unroll
        for (int j = 0; j < 8; j++) {
            o[j]     += wts[n] * bf2f(a[j]);
            o[8 + j] += wts[n] * bf2f(b[j]);
        }
    }

    ushort8 oa, ob;
#pragma unroll
    for (int j = 0; j < 8; j++) { oa[j] = f2bf(o[j] * inv); ob[j] = f2bf(o[8 + j] * inv); }
    ushort8* op = (ushort8*)(outp + (long)p * C + cb);
    op[0] = oa;
    op[1] = ob;
}

// ---------------- launch --------------------------------------------------------
extern "C" void kernel_launch(void* const* d_in, const int* in_sizes, int n_in,
                              void* d_out, int out_size, void* d_ws, size_t ws_size,
                              hipStream_t stream) {
    const float* x    = (const float*)d_in[0];
    const float* Wq   = (const float*)d_in[1];
    const float* bq   = (const float*)d_in[2];
    const float* Wk   = (const float*)d_in[3];
    const float* bk   = (const float*)d_in[4];
    const float* Wv   = (const float*)d_in[5];
    const float* bv   = (const float*)d_in[6];
    const float* qn_w = (const float*)d_in[7];
    const float* kn_w = (const float*)d_in[8];
    const float* eb   = (const float*)d_in[9];
    const float* Wo   = (const float*)d_in[10];
    const float* bo   = (const float*)d_in[11];
    // d_in[12] = num_frames (8) — hard-coded as T

    char* ws = (char*)d_ws;
    ushort_t* xbf  = (ushort_t*)ws;                               // L*C bf16 = 16 MB
    ushort_t* WqT  = (ushort_t*)(ws + (size_t)L * C * 2);         // 4 x 2 MB
    ushort_t* WkT  = WqT + (size_t)C * C;
    ushort_t* WvT  = WkT + (size_t)C * C;
    ushort_t* WoT  = WvT + (size_t)C * C;
    ushort_t* qraw = WoT + (size_t)C * C;                         // 3 x 16 MB
    ushort_t* kraw = qraw + (size_t)L * C;
    ushort_t* vraw = kraw + (size_t)L * C;
    ushort_t* aout = vraw + (size_t)L * C;                        // 16 MB
    float* outp = (float*)d_out;

    cvt_kernel<<<(L * C / 8 + 255) / 256, 256, 0, stream>>>(x, xbf, L * C / 8);
    transpose4_kernel<<<dim3(32, 32, 4), 256, 0, stream>>>(Wq, Wk, Wv, Wo,
                                                           WqT, WkT, WvT, WoT);
    gemm_qkv_kernel<<<dim3(L / 128, C / 128, 3), 256, 0, stream>>>(
        xbf, WqT, WkT, WvT, bq, bk, bv, qraw, kraw, vraw);
    attn_kernel<<<L / 4, 256, 0, stream>>>(qraw, kraw, vraw, qn_w, kn_w, eb, aout);
    gemm_o_kernel<<<dim3(L / 128, C / 128), 256, 0, stream>>>(aout, WoT, bo, outp);
}

// Round 4
// 241.020 us; speedup vs baseline: 1.0277x; 1.0277x over previous
//
#include <hip/hip_runtime.h>
#include <hip/hip_bf16.h>

typedef __bf16 bf16x8 __attribute__((ext_vector_type(8)));
typedef float f32x4 __attribute__((ext_vector_type(4)));
typedef unsigned short ushort8 __attribute__((ext_vector_type(8)));
typedef unsigned short ushort_t;

#define AS3(p) ((__attribute__((address_space(3))) void*)(p))
#define AS1(p) ((const __attribute__((address_space(1))) void*)(p))

constexpr int L = 8192;
constexpr int C = 1024;   // = H*D = inner
constexpr int T = 8;
constexpr int S = 1024;   // L / T

__device__ __forceinline__ float bf2f(ushort_t u) {
    return __uint_as_float(((unsigned)u) << 16);
}
__device__ __forceinline__ ushort_t f2bf(float f) {
    unsigned x = __float_as_uint(f);
    unsigned r = (x + 0x7fffu + ((x >> 16) & 1u)) >> 16;  // RNE
    return (ushort_t)r;
}

// ---------------- f32 -> bf16 convert -----------------------------------------
__global__ __launch_bounds__(256) void cvt_kernel(const float* __restrict__ in,
                                                  ushort_t* __restrict__ out, int n8) {
    int i = blockIdx.x * 256 + threadIdx.x;
    if (i >= n8) return;
    const float4* p = (const float4*)in + (long)i * 2;
    float4 a = p[0], b = p[1];
    ushort8 o;
    o[0] = f2bf(a.x); o[1] = f2bf(a.y); o[2] = f2bf(a.z); o[3] = f2bf(a.w);
    o[4] = f2bf(b.x); o[5] = f2bf(b.y); o[6] = f2bf(b.z); o[7] = f2bf(b.w);
    ((ushort8*)out)[i] = o;
}

// ---------------- W [K][N] f32 -> Wt [N][K] bf16 (4 matrices) ------------------
__global__ __launch_bounds__(256) void transpose4_kernel(
    const float* __restrict__ w0, const float* __restrict__ w1,
    const float* __restrict__ w2, const float* __restrict__ w3,
    ushort_t* __restrict__ o0, ushort_t* __restrict__ o1,
    ushort_t* __restrict__ o2, ushort_t* __restrict__ o3) {
    int z = blockIdx.z;
    const float* W = z == 0 ? w0 : z == 1 ? w1 : z == 2 ? w2 : w3;
    ushort_t* O    = z == 0 ? o0 : z == 1 ? o1 : z == 2 ? o2 : o3;
    __shared__ float tile[32][33];
    int tx = threadIdx.x & 31, ty = threadIdx.x >> 5;
    int bx = blockIdx.x * 32, by = blockIdx.y * 32;
#pragma unroll
    for (int i = 0; i < 32; i += 8)
        tile[ty + i][tx] = W[(long)(by + ty + i) * C + bx + tx];
    __syncthreads();
#pragma unroll
    for (int i = 0; i < 32; i += 8)
        O[(long)(bx + ty + i) * C + by + tx] = f2bf(tile[tx][ty + i]);
}

// ---------------- 8-phase GEMM: A[M,K] bf16 x Bt[N,K] bf16 ---------------------
// BM=256 BN=128 BK=64, 512 thr (8 waves 2x4), 3 LDS buffers (2-tile prefetch
// depth -> steady-state s_waitcnt vmcnt(6), never 0). T2 chunk-XOR swizzle
// (slot ^= row&7) applied as: linear global_load_lds dest + inverse-swizzled
// global SOURCE + swizzled ds_read (rule #21). T5 setprio around MFMA clusters.
constexpr int BUFB = 49152;  // 32KB A + 16KB B per buffer

#define GBAR() asm volatile("s_barrier" ::: "memory")
#define VMBAR6() asm volatile("s_waitcnt vmcnt(6)\ns_barrier" ::: "memory")
#define VMBAR0() asm volatile("s_waitcnt vmcnt(0)\ns_barrier" ::: "memory")

template <bool BF16_OUT>
__device__ __forceinline__ void gemm8_body(const ushort_t* __restrict__ A,
                                           const ushort_t* __restrict__ Bt,
                                           const float* __restrict__ bias,
                                           void* __restrict__ Cv,
                                           int M, int N, int K, int bx, int by) {
    __shared__ char lds[3 * BUFB];
    const int tid = threadIdx.x;
    const int wave = tid >> 6, lane = tid & 63;
    const int wm = wave >> 2, wn = wave & 3;
    const int bm0 = bx * 256, bn0 = by * 128;
    const int KT = K >> 6;  // BK=64

    // staging: A = 2048 16B chunks (4/thread), B = 1024 (2/thread).
    // chunk c -> row=c>>3, lds slot=c&7 holds global col-block (c&7)^(row&7).
    const char* Ab = (const char*)A;
    const char* Bb = (const char*)Bt;
    long aSrc[4], bSrc[2];
#pragma unroll
    for (int j = 0; j < 4; j++) {
        int c = tid + j * 512, row = c >> 3, scol = (c & 7) ^ (row & 7);
        aSrc[j] = ((long)(bm0 + row) * K + scol * 8) * 2;
    }
#pragma unroll
    for (int j = 0; j < 2; j++) {
        int c = tid + j * 512, row = c >> 3, scol = (c & 7) ^ (row & 7);
        bSrc[j] = ((long)(bn0 + row) * K + scol * 8) * 2;
    }
    const unsigned wOff = wave * 1024u;

#define STAGE_A(it2, cb, j) \
    __builtin_amdgcn_global_load_lds(AS1(Ab + aSrc[j] + (long)(it2) * 128), \
        AS3(lds + (cb) * BUFB + (j) * 8192 + wOff), 16, 0, 0)
#define STAGE_B(it2, cb, j) \
    __builtin_amdgcn_global_load_lds(AS1(Bb + bSrc[j] + (long)(it2) * 128), \
        AS3(lds + (cb) * BUFB + 32768 + (j) * 8192 + wOff), 16, 0, 0)

    // read-side swizzled column offsets (row&7 == lane&7 for all frag rows)
    const unsigned cs0 = (((lane >> 4)) ^ (lane & 7)) * 16u;
    const unsigned cs1 = (((lane >> 4) + 4) ^ (lane & 7)) * 16u;
    const unsigned rA = (wm * 128 + (lane & 15)) * 128u;
    const unsigned rB = (wn * 32 + (lane & 15)) * 128u;

    f32x4 acc[8][2] = {};
    bf16x8 af[4][2], bf0[2], bf1[2];

    // prologue: tile0 -> buf0, tile1 -> buf1
#pragma unroll
    for (int j = 0; j < 4; j++) STAGE_A(0, 0, j);
#pragma unroll
    for (int j = 0; j < 2; j++) STAGE_B(0, 0, j);
#pragma unroll
    for (int j = 0; j < 4; j++) STAGE_A(1, 1, j);
#pragma unroll
    for (int j = 0; j < 2; j++) STAGE_B(1, 1, j);
    VMBAR6();  // wait tile0 (leave tile1's 6 in flight)

    int c = 0;
    for (int it = 0; it < KT; ++it) {
        const char* bA = lds + c * BUFB;
        const char* bB = bA + 32768;
        const int c2 = (c == 0) ? 2 : c - 1;  // (c+2)%3
        const int it2 = it + 2;
        const bool stage = it2 < KT;

        // ---- phase 0: A rows 0..63 + B col-block 0; stage A j0,j1
#pragma unroll
        for (int q = 0; q < 4; q++) {
            af[q][0] = *(const bf16x8*)(bA + rA + q * 2048 + cs0);
            af[q][1] = *(const bf16x8*)(bA + rA + q * 2048 + cs1);
        }
        bf0[0] = *(const bf16x8*)(bB + rB + cs0);
        bf0[1] = *(const bf16x8*)(bB + rB + cs1);
        if (stage) { STAGE_A(it2, c2, 0); STAGE_A(it2, c2, 1); }
        GBAR();
        __builtin_amdgcn_s_setprio(1);
#pragma unroll
        for (int q = 0; q < 4; q++) {
            acc[q][0] = __builtin_amdgcn_mfma_f32_16x16x32_bf16(af[q][0], bf0[0], acc[q][0], 0, 0, 0);
            acc[q][0] = __builtin_amdgcn_mfma_f32_16x16x32_bf16(af[q][1], bf0[1], acc[q][0], 0, 0, 0);
        }
        __builtin_amdgcn_s_setprio(0);
        GBAR();

        // ---- phase 1: B col-block 1; stage A j2,j3
        bf1[0] = *(const bf16x8*)(bB + rB + 2048 + cs0);
        bf1[1] = *(const bf16x8*)(bB + rB + 2048 + cs1);
        if (stage) { STAGE_A(it2, c2, 2); STAGE_A(it2, c2, 3); }
        GBAR();
        __builtin_amdgcn_s_setprio(1);
#pragma unroll
        for (int q = 0; q < 4; q++) {
            acc[q][1] = __builtin_amdgcn_mfma_f32_16x16x32_bf16(af[q][0], bf1[0], acc[q][1], 0, 0, 0);
            acc[q][1] = __builtin_amdgcn_mfma_f32_16x16x32_bf16(af[q][1], bf1[1], acc[q][1], 0, 0, 0);
        }
        __builtin_amdgcn_s_setprio(0);
        GBAR();

        // ---- phase 2: A rows 64..127; stage B j0,j1
#pragma unroll
        for (int q = 0; q < 4; q++) {
            af[q][0] = *(const bf16x8*)(bA + rA + (4 + q) * 2048 + cs0);
            af[q][1] = *(const bf16x8*)(bA + rA + (4 + q) * 2048 + cs1);
        }
        if (stage) { STAGE_B(it2, c2, 0); STAGE_B(it2, c2, 1); }
        GBAR();
        __builtin_amdgcn_s_setprio(1);
#pragma unroll
        for (int q = 0; q < 4; q++) {
            acc[4 + q][0] = __builtin_amdgcn_mfma_f32_16x16x32_bf16(af[q][0], bf0[0], acc[4 + q][0], 0, 0, 0);
            acc[4 + q][0] = __builtin_amdgcn_mfma_f32_16x16x32_bf16(af[q][1], bf0[1], acc[4 + q][0], 0, 0, 0);
        }
        __builtin_amdgcn_s_setprio(0);
        GBAR();

        // ---- phase 3 (no reads, no stage)
        __builtin_amdgcn_s_setprio(1);
#pragma unroll
        for (int q = 0; q < 4; q++) {
            acc[4 + q][1] = __builtin_amdgcn_mfma_f32_16x16x32_bf16(af[q][0], bf1[0], acc[4 + q][1], 0, 0, 0);
            acc[4 + q][1] = __builtin_amdgcn_mfma_f32_16x16x32_bf16(af[q][1], bf1[1], acc[4 + q][1], 0, 0, 0);
        }
        __builtin_amdgcn_s_setprio(0);

        // ---- iter end: wait for tile it+1 (counted; leave it+2's 6 in flight)
        if (it < KT - 1) {
            if (stage) VMBAR6(); else VMBAR0();
        }
        c = (c == 2) ? 0 : c + 1;
    }

    // epilogue: C/D layout col=lane&15, row=(lane>>4)*4+r
    const int r0 = bm0 + wm * 128 + (lane >> 4) * 4;
    const int c0 = bn0 + wn * 32 + (lane & 15);
#pragma unroll
    for (int n = 0; n < 2; n++) {
        const int col = c0 + n * 16;
        const float bia = bias[col];
#pragma unroll
        for (int m = 0; m < 8; m++) {
            const int row = r0 + m * 16;
#pragma unroll
            for (int r = 0; r < 4; r++) {
                float val = acc[m][n][r] + bia;
                if (BF16_OUT)
                    ((ushort_t*)Cv)[(long)(row + r) * N + col] = f2bf(val);
                else
                    ((float*)Cv)[(long)(row + r) * N + col] = val;
            }
        }
    }
#undef STAGE_A
#undef STAGE_B
}

__global__ __launch_bounds__(512) void gemm_qkv_kernel(
    const ushort_t* __restrict__ xbf,
    const ushort_t* __restrict__ WqT, const ushort_t* __restrict__ WkT,
    const ushort_t* __restrict__ WvT,
    const float* __restrict__ bq, const float* __restrict__ bk,
    const float* __restrict__ bv,
    ushort_t* __restrict__ q, ushort_t* __restrict__ k, ushort_t* __restrict__ v) {
    const int z = blockIdx.z;
    const ushort_t* Bt = z == 0 ? WqT : z == 1 ? WkT : WvT;
    const float* bias  = z == 0 ? bq : z == 1 ? bk : bv;
    ushort_t* out      = z == 0 ? q : z == 1 ? k : v;
    gemm8_body<true>(xbf, Bt, bias, out, L, C, C, blockIdx.x, blockIdx.y);
}

__global__ __launch_bounds__(512) void gemm_o_kernel(
    const ushort_t* __restrict__ a, const ushort_t* __restrict__ WoT,
    const float* __restrict__ bo, float* __restrict__ outp) {
    gemm8_body<false>(a, WoT, bo, outp, L, C, C, blockIdx.x, blockIdx.y);
}

// ---------------- per-row rsqrt precompute (q and k) ---------------------------
__global__ __launch_bounds__(256) void rownorm_kernel(
    const ushort_t* __restrict__ q, const ushort_t* __restrict__ k,
    float* __restrict__ rq, float* __restrict__ rk) {
    const int wave = threadIdx.x >> 6, lane = threadIdx.x & 63;
    const int p = blockIdx.x * 4 + wave;
    const ushort8* qp = (const ushort8*)(q + (long)p * C + lane * 16);
    const ushort8* kp = (const ushort8*)(k + (long)p * C + lane * 16);
    ushort8 qa = qp[0], qb = qp[1], ka = kp[0], kb = kp[1];
    float sq = 0.f, sk = 0.f;
#pragma unroll
    for (int j = 0; j < 8; j++) {
        float a = bf2f(qa[j]), b = bf2f(qb[j]);
        sq += a * a + b * b;
        float c2 = bf2f(ka[j]), d = bf2f(kb[j]);
        sk += c2 * c2 + d * d;
    }
#pragma unroll
    for (int m = 1; m < 64; m <<= 1) { sq += __shfl_xor(sq, m); sk += __shfl_xor(sk, m); }
    if (lane == 0) {
        rq[p] = rsqrtf(sq * (1.0f / C) + 1e-6f);
        rk[p] = rsqrtf(sk * (1.0f / C) + 1e-6f);
    }
}

// ---------------- fused small-world attention (norms precomputed) --------------
// T1 XCD swizzle: frame f = bid&7 -> all blocks of frame f land on XCD f;
// all 12 spatial-neighbor k/v rows then live in that XCD's L2 (4MB/frame).
__global__ __launch_bounds__(256) void attn_kernel(
    const ushort_t* __restrict__ qraw, const ushort_t* __restrict__ kraw,
    const ushort_t* __restrict__ vraw,
    const float* __restrict__ qn_w, const float* __restrict__ kn_w,
    const float* __restrict__ eb, const float* __restrict__ rqA,
    const float* __restrict__ rkA, ushort_t* __restrict__ outp) {
    const int wave = threadIdx.x >> 6, lane = threadIdx.x & 63;
    const int bid = blockIdx.x;
    const int t = bid & 7;
    const int s = (bid >> 3) * 4 + wave;
    const int p = (t << 10) | s;
    const int h = lane >> 2;
    const int cb = lane * 16;

    // ---- q row, scaled by rq * qn_w * kn_w
    float qf[16];
    {
        const ushort8* qp = (const ushort8*)(qraw + (long)p * C + cb);
        ushort8 a = qp[0], b = qp[1];
#pragma unroll
        for (int j = 0; j < 8; j++) { qf[j] = bf2f(a[j]); qf[8 + j] = bf2f(b[j]); }
    }
    const float rq = rqA[p];
#pragma unroll
    for (int j = 0; j < 16; j++) qf[j] *= rq * qn_w[cb + j] * kn_w[cb + j];

    // ---- neighbor positions
    const int SHF[16] = {1, -1, 2, -2, 4, -4, 8, -8, 16, -16, 32, -32, 1, -1, 2, -2};
    int pp[16];
#pragma unroll
    for (int n = 0; n < 16; n++) {
        if (n < 12) pp[n] = (p & ~(S - 1)) | ((s + SHF[n]) & (S - 1));
        else        pp[n] = (((t + SHF[n]) & (T - 1)) << 10) | s;
    }

    // ---- scores (k-row rsqrt precomputed)
    float sc[16];
#pragma unroll
    for (int n = 0; n < 16; n++) {
        const ushort8* kp = (const ushort8*)(kraw + (long)pp[n] * C + cb);
        ushort8 a = kp[0], b = kp[1];
        float dot = 0.f;
#pragma unroll
        for (int j = 0; j < 8; j++) dot += qf[j] * bf2f(a[j]) + qf[8 + j] * bf2f(b[j]);
        dot += __shfl_xor(dot, 1);
        dot += __shfl_xor(dot, 2);
        sc[n] = dot * (rkA[pp[n]] * 0.125f) + eb[h * 16 + n];
    }

    // ---- softmax over 16 shifts
    float mx = sc[0];
#pragma unroll
    for (int n = 1; n < 16; n++) mx = fmaxf(mx, sc[n]);
    float wts[16], den = 0.f;
#pragma unroll
    for (int n = 0; n < 16; n++) { wts[n] = __expf(sc[n] - mx); den += wts[n]; }
    const float inv = 1.0f / den;

    // ---- weighted V
    float o[16] = {};
#pragma unroll
    for (int n = 0; n < 16; n++) {
        const ushort8* vp = (const ushort8*)(vraw + (long)pp[n] * C + cb);
        ushort8 a = vp[0], b = vp[1];
#pragma unroll
        for (int j = 0; j < 8; j++) {
            o[j]     += wts[n] * bf2f(a[j]);
            o[8 + j] += wts[n] * bf2f(b[j]);
        }
    }

    ushort8 oa, ob;
#pragma unroll
    for (int j = 0; j < 8; j++) { oa[j] = f2bf(o[j] * inv); ob[j] = f2bf(o[8 + j] * inv); }
    ushort8* op = (ushort8*)(outp + (long)p * C + cb);
    op[0] = oa;
    op[1] = ob;
}

// ---------------- launch --------------------------------------------------------
extern "C" void kernel_launch(void* const* d_in, const int* in_sizes, int n_in,
                              void* d_out, int out_size, void* d_ws, size_t ws_size,
                              hipStream_t stream) {
    const float* x    = (const float*)d_in[0];
    const float* Wq   = (const float*)d_in[1];
    const float* bq   = (const float*)d_in[2];
    const float* Wk   = (const float*)d_in[3];
    const float* bk   = (const float*)d_in[4];
    const float* Wv   = (const float*)d_in[5];
    const float* bv   = (const float*)d_in[6];
    const float* qn_w = (const float*)d_in[7];
    const float* kn_w = (const float*)d_in[8];
    const float* eb   = (const float*)d_in[9];
    const float* Wo   = (const float*)d_in[10];
    const float* bo   = (const float*)d_in[11];

    char* ws = (char*)d_ws;
    ushort_t* xbf  = (ushort_t*)ws;                               // 16 MB
    ushort_t* WqT  = (ushort_t*)(ws + (size_t)L * C * 2);         // 4 x 2 MB
    ushort_t* WkT  = WqT + (size_t)C * C;
    ushort_t* WvT  = WkT + (size_t)C * C;
    ushort_t* WoT  = WvT + (size_t)C * C;
    ushort_t* qraw = WoT + (size_t)C * C;                         // 3 x 16 MB
    ushort_t* kraw = qraw + (size_t)L * C;
    ushort_t* vraw = kraw + (size_t)L * C;
    ushort_t* aout = vraw + (size_t)L * C;                        // 16 MB
    float* rqArr   = (float*)(aout + (size_t)L * C);              // 32 KB
    float* rkArr   = rqArr + L;                                   // 32 KB
    float* outp = (float*)d_out;

    cvt_kernel<<<(L * C / 8 + 255) / 256, 256, 0, stream>>>(x, xbf, L * C / 8);
    transpose4_kernel<<<dim3(32, 32, 4), 256, 0, stream>>>(Wq, Wk, Wv, Wo,
                                                           WqT, WkT, WvT, WoT);
    gemm_qkv_kernel<<<dim3(L / 256, C / 128, 3), 512, 0, stream>>>(
        xbf, WqT, WkT, WvT, bq, bk, bv, qraw, kraw, vraw);
    rownorm_kernel<<<L / 4, 256, 0, stream>>>(qraw, kraw, rqArr, rkArr);
    attn_kernel<<<L / 4, 256, 0, stream>>>(qraw, kraw, vraw, qn_w, kn_w, eb,
                                           rqArr, rkArr, aout);
    gemm_o_kernel<<<dim3(L / 256, C / 128), 512, 0, stream>>>(aout, WoT, bo, outp);
}

// Round 5
// 237.524 us; speedup vs baseline: 1.0428x; 1.0147x over previous
//
#include <hip/hip_runtime.h>
#include <hip/hip_bf16.h>

typedef __bf16 bf16x8 __attribute__((ext_vector_type(8)));
typedef float f32x4 __attribute__((ext_vector_type(4)));
typedef unsigned short ushort8 __attribute__((ext_vector_type(8)));
typedef unsigned short ushort_t;

#define AS3(p) ((__attribute__((address_space(3))) void*)(p))
#define AS1(p) ((const __attribute__((address_space(1))) void*)(p))

constexpr int L = 8192;
constexpr int C = 1024;   // = H*D = inner
constexpr int T = 8;
constexpr int S = 1024;   // L / T

__device__ __forceinline__ float bf2f(ushort_t u) {
    return __uint_as_float(((unsigned)u) << 16);
}
__device__ __forceinline__ ushort_t f2bf(float f) {
    unsigned x = __float_as_uint(f);
    unsigned r = (x + 0x7fffu + ((x >> 16) & 1u)) >> 16;  // RNE
    return (ushort_t)r;
}

// ---------------- f32 -> bf16 convert -----------------------------------------
__global__ __launch_bounds__(256) void cvt_kernel(const float* __restrict__ in,
                                                  ushort_t* __restrict__ out, int n8) {
    int i = blockIdx.x * 256 + threadIdx.x;
    if (i >= n8) return;
    const float4* p = (const float4*)in + (long)i * 2;
    float4 a = p[0], b = p[1];
    ushort8 o;
    o[0] = f2bf(a.x); o[1] = f2bf(a.y); o[2] = f2bf(a.z); o[3] = f2bf(a.w);
    o[4] = f2bf(b.x); o[5] = f2bf(b.y); o[6] = f2bf(b.z); o[7] = f2bf(b.w);
    ((ushort8*)out)[i] = o;
}

// ---------------- W [K][N] f32 -> Wt [N][K] bf16 (4 matrices) ------------------
__global__ __launch_bounds__(256) void transpose4_kernel(
    const float* __restrict__ w0, const float* __restrict__ w1,
    const float* __restrict__ w2, const float* __restrict__ w3,
    ushort_t* __restrict__ o0, ushort_t* __restrict__ o1,
    ushort_t* __restrict__ o2, ushort_t* __restrict__ o3) {
    int z = blockIdx.z;
    const float* W = z == 0 ? w0 : z == 1 ? w1 : z == 2 ? w2 : w3;
    ushort_t* O    = z == 0 ? o0 : z == 1 ? o1 : z == 2 ? o2 : o3;
    __shared__ float tile[32][33];
    int tx = threadIdx.x & 31, ty = threadIdx.x >> 5;
    int bx = blockIdx.x * 32, by = blockIdx.y * 32;
#pragma unroll
    for (int i = 0; i < 32; i += 8)
        tile[ty + i][tx] = W[(long)(by + ty + i) * C + bx + tx];
    __syncthreads();
#pragma unroll
    for (int i = 0; i < 32; i += 8)
        O[(long)(bx + ty + i) * C + by + tx] = f2bf(tile[tx][ty + i]);
}

// ---------------- GEMM: A[M,K] bf16 x Bt[N,K] bf16 -----------------------------
// BM=256 BN=128 BK=32, 256 thr (4 waves 2Mx2N), per-wave 128x64 (m=8,n=4 frags).
// 3 LDS buffers x 24KB (2-tile prefetch depth -> steady s_waitcnt vmcnt(6)).
// LDS rows are 64B: each frag ds_read_b128 covers a contiguous 1KB region
// bijectively -> conflict-free, linear staging (no swizzle needed).
// One barrier per K-iter. T5 setprio around MFMA cluster.
#define VMBAR6() asm volatile("s_waitcnt vmcnt(6)\ns_barrier" ::: "memory")
#define VMBAR0() asm volatile("s_waitcnt vmcnt(0)\ns_barrier" ::: "memory")

template <bool BF16_OUT>
__device__ __forceinline__ void gemm_body(const ushort_t* __restrict__ A,
                                          const ushort_t* __restrict__ Bt,
                                          const float* __restrict__ bias,
                                          void* __restrict__ Cv,
                                          int K, int N, int bx, int by) {
    __shared__ char lds[3 * 24576];
    const int tid = threadIdx.x;
    const int wave = tid >> 6, lane = tid & 63;
    const int wm = wave >> 1, wn = wave & 1;
    const long bm0 = (long)bx * 256, bn0 = (long)by * 128;
    const int KT = K >> 5;  // BK=32

    // staging: A = 1024 16B chunks (4/thread), B = 512 (2/thread), all linear.
    // chunk c -> row=c>>2, kslot=c&3; LDS byte = c*16.
    const char* Ab = (const char*)A;
    const char* Bb = (const char*)Bt;
    long aSrc[4], bSrc[2];
#pragma unroll
    for (int j = 0; j < 4; j++) {
        int cc = tid + j * 256;
        aSrc[j] = (bm0 + (cc >> 2)) * (long)(K * 2) + (cc & 3) * 16;
    }
#pragma unroll
    for (int j = 0; j < 2; j++) {
        int cc = tid + j * 256;
        bSrc[j] = (bn0 + (cc >> 2)) * (long)(K * 2) + (cc & 3) * 16;
    }
    const unsigned wOff = wave * 1024u;

#define STG(buf, it2)                                                          \
    do {                                                                       \
        const long kb_ = (long)(it2) * 64;                                     \
        char* bs_ = lds + (buf) * 24576;                                       \
        _Pragma("unroll") for (int j = 0; j < 4; j++)                          \
            __builtin_amdgcn_global_load_lds(AS1(Ab + aSrc[j] + kb_),          \
                AS3(bs_ + j * 4096 + wOff), 16, 0, 0);                         \
        _Pragma("unroll") for (int j = 0; j < 2; j++)                          \
            __builtin_amdgcn_global_load_lds(AS1(Bb + bSrc[j] + kb_),          \
                AS3(bs_ + 16384 + j * 4096 + wOff), 16, 0, 0);                 \
    } while (0)

    // fragment read offsets: A-frag lane: row=lane&15 (+q*16), kslot=lane>>4
    const unsigned rdA = (wm * 128 + (lane & 15)) * 64u + (lane >> 4) * 16u;
    const unsigned rdB = 16384u + (wn * 64 + (lane & 15)) * 64u + (lane >> 4) * 16u;

    f32x4 acc[8][4] = {};

    // prologue: tile0 -> buf0, tile1 -> buf1
    STG(0, 0);
    STG(1, 1);
    VMBAR6();  // tile0 complete (tile1's 6 stay in flight)

    int c = 0;
    for (int it = 0; it < KT; ++it) {
        const int c2 = (c >= 1) ? c - 1 : 2;  // (c+2)%3
        if (it + 2 < KT) STG(c2, it + 2);

        const char* bs = lds + c * 24576;
        bf16x8 af[8], bfr[4];
#pragma unroll
        for (int q = 0; q < 8; q++)
            af[q] = *(const bf16x8*)(bs + rdA + q * 1024);
#pragma unroll
        for (int j = 0; j < 4; j++)
            bfr[j] = *(const bf16x8*)(bs + rdB + j * 1024);

        __builtin_amdgcn_s_setprio(1);
#pragma unroll
        for (int q = 0; q < 8; q++)
#pragma unroll
            for (int j = 0; j < 4; j++)
                acc[q][j] = __builtin_amdgcn_mfma_f32_16x16x32_bf16(af[q], bfr[j],
                                                                    acc[q][j], 0, 0, 0);
        __builtin_amdgcn_s_setprio(0);

        if (it + 2 < KT)      VMBAR6();  // tile it+1 ready, it+2's 6 in flight
        else if (it + 1 < KT) VMBAR0();  // drain last tile
        c = (c >= 2) ? 0 : c + 1;
    }

    // epilogue: C/D layout col=lane&15, row=(lane>>4)*4+r
    const int r0 = (int)bm0 + wm * 128 + (lane >> 4) * 4;
    const int c0 = (int)bn0 + wn * 64 + (lane & 15);
#pragma unroll
    for (int j = 0; j < 4; j++) {
        const int col = c0 + j * 16;
        const float bia = bias[col];
#pragma unroll
        for (int q = 0; q < 8; q++) {
            const int row = r0 + q * 16;
#pragma unroll
            for (int r = 0; r < 4; r++) {
                float val = acc[q][j][r] + bia;
                if (BF16_OUT)
                    ((ushort_t*)Cv)[(long)(row + r) * N + col] = f2bf(val);
                else
                    ((float*)Cv)[(long)(row + r) * N + col] = val;
            }
        }
    }
#undef STG
}

__global__ __launch_bounds__(256, 2) void gemm_qkv_kernel(
    const ushort_t* __restrict__ xbf,
    const ushort_t* __restrict__ WqT, const ushort_t* __restrict__ WkT,
    const ushort_t* __restrict__ WvT,
    const float* __restrict__ bq, const float* __restrict__ bk,
    const float* __restrict__ bv,
    ushort_t* __restrict__ q, ushort_t* __restrict__ k, ushort_t* __restrict__ v) {
    const int z = blockIdx.z;
    const ushort_t* Bt = z == 0 ? WqT : z == 1 ? WkT : WvT;
    const float* bias  = z == 0 ? bq : z == 1 ? bk : bv;
    ushort_t* out      = z == 0 ? q : z == 1 ? k : v;
    gemm_body<true>(xbf, Bt, bias, out, C, C, blockIdx.x, blockIdx.y);
}

__global__ __launch_bounds__(256, 2) void gemm_o_kernel(
    const ushort_t* __restrict__ a, const ushort_t* __restrict__ WoT,
    const float* __restrict__ bo, float* __restrict__ outp) {
    gemm_body<false>(a, WoT, bo, outp, C, C, blockIdx.x, blockIdx.y);
}

// ---------------- per-row rsqrt precompute (k only) ----------------------------
__global__ __launch_bounds__(256) void rownorm_k_kernel(
    const ushort_t* __restrict__ k, float* __restrict__ rk) {
    const int wave = threadIdx.x >> 6, lane = threadIdx.x & 63;
    const int p = blockIdx.x * 4 + wave;
    const ushort8* kp = (const ushort8*)(k + (long)p * C + lane * 16);
    ushort8 ka = kp[0], kb = kp[1];
    float sk = 0.f;
#pragma unroll
    for (int j = 0; j < 8; j++) {
        float c2 = bf2f(ka[j]), d = bf2f(kb[j]);
        sk += c2 * c2 + d * d;
    }
#pragma unroll
    for (int m = 1; m < 64; m <<= 1) sk += __shfl_xor(sk, m);
    if (lane == 0) rk[p] = rsqrtf(sk * (1.0f / C) + 1e-6f);
}

// ---------------- fused small-world attention ----------------------------------
// T1 XCD swizzle: frame f = bid&7 -> all blocks of frame f land on XCD f;
// spatial-neighbor k/v rows then live in that XCD's L2.
__global__ __launch_bounds__(256) void attn_kernel(
    const ushort_t* __restrict__ qraw, const ushort_t* __restrict__ kraw,
    const ushort_t* __restrict__ vraw,
    const float* __restrict__ qn_w, const float* __restrict__ kn_w,
    const float* __restrict__ eb, const float* __restrict__ rkA,
    ushort_t* __restrict__ outp) {
    const int wave = threadIdx.x >> 6, lane = threadIdx.x & 63;
    const int bid = blockIdx.x;
    const int t = bid & 7;
    const int s = (bid >> 3) * 4 + wave;
    const int p = (t << 10) | s;
    const int h = lane >> 2;
    const int cb = lane * 16;

    // ---- q row: RMS over C=1024 (full-wave reduce), fold qn_w*kn_w*rstd_q
    float qf[16];
    {
        const ushort8* qp = (const ushort8*)(qraw + (long)p * C + cb);
        ushort8 a = qp[0], b = qp[1];
#pragma unroll
        for (int j = 0; j < 8; j++) { qf[j] = bf2f(a[j]); qf[8 + j] = bf2f(b[j]); }
    }
    float ss = 0.f;
#pragma unroll
    for (int j = 0; j < 16; j++) ss += qf[j] * qf[j];
#pragma unroll
    for (int m = 1; m < 64; m <<= 1) ss += __shfl_xor(ss, m);
    const float rq = rsqrtf(ss * (1.0f / C) + 1e-6f);
#pragma unroll
    for (int j = 0; j < 16; j++) qf[j] *= rq * qn_w[cb + j] * kn_w[cb + j];

    // ---- neighbor positions
    const int SHF[16] = {1, -1, 2, -2, 4, -4, 8, -8, 16, -16, 32, -32, 1, -1, 2, -2};
    int pp[16];
#pragma unroll
    for (int n = 0; n < 16; n++) {
        if (n < 12) pp[n] = (p & ~(S - 1)) | ((s + SHF[n]) & (S - 1));
        else        pp[n] = (((t + SHF[n]) & (T - 1)) << 10) | s;
    }

    // ---- scores (k-row rsqrt precomputed)
    float sc[16];
#pragma unroll
    for (int n = 0; n < 16; n++) {
        const ushort8* kp = (const ushort8*)(kraw + (long)pp[n] * C + cb);
        ushort8 a = kp[0], b = kp[1];
        float dot = 0.f;
#pragma unroll
        for (int j = 0; j < 8; j++) dot += qf[j] * bf2f(a[j]) + qf[8 + j] * bf2f(b[j]);
        dot += __shfl_xor(dot, 1);
        dot += __shfl_xor(dot, 2);
        sc[n] = dot * (rkA[pp[n]] * 0.125f) + eb[h * 16 + n];
    }

    // ---- softmax over 16 shifts
    float mx = sc[0];
#pragma unroll
    for (int n = 1; n < 16; n++) mx = fmaxf(mx, sc[n]);
    float wts[16], den = 0.f;
#pragma unroll
    for (int n = 0; n < 16; n++) { wts[n] = __expf(sc[n] - mx); den += wts[n]; }
    const float inv = 1.0f / den;

    // ---- weighted V
    float o[16] = {};
#pragma unroll
    for (int n = 0; n < 16; n++) {
        const ushort8* vp = (const ushort8*)(vraw + (long)pp[n] * C + cb);
        ushort8 a = vp[0], b = vp[1];
#pragma unroll
        for (int j = 0; j < 8; j++) {
            o[j]     += wts[n] * bf2f(a[j]);
            o[8 + j] += wts[n] * bf2f(b[j]);
        }
    }

    ushort8 oa, ob;
#pragma unroll
    for (int j = 0; j < 8; j++) { oa[j] = f2bf(o[j] * inv); ob[j] = f2bf(o[8 + j] * inv); }
    ushort8* op = (ushort8*)(outp + (long)p * C + cb);
    op[0] = oa;
    op[1] = ob;
}

// ---------------- launch --------------------------------------------------------
extern "C" void kernel_launch(void* const* d_in, const int* in_sizes, int n_in,
                              void* d_out, int out_size, void* d_ws, size_t ws_size,
                              hipStream_t stream) {
    const float* x    = (const float*)d_in[0];
    const float* Wq   = (const float*)d_in[1];
    const float* bq   = (const float*)d_in[2];
    const float* Wk   = (const float*)d_in[3];
    const float* bk   = (const float*)d_in[4];
    const float* Wv   = (const float*)d_in[5];
    const float* bv   = (const float*)d_in[6];
    const float* qn_w = (const float*)d_in[7];
    const float* kn_w = (const float*)d_in[8];
    const float* eb   = (const float*)d_in[9];
    const float* Wo   = (const float*)d_in[10];
    const float* bo   = (const float*)d_in[11];

    char* ws = (char*)d_ws;
    ushort_t* xbf  = (ushort_t*)ws;                               // 16 MB
    ushort_t* WqT  = (ushort_t*)(ws + (size_t)L * C * 2);         // 4 x 2 MB
    ushort_t* WkT  = WqT + (size_t)C * C;
    ushort_t* WvT  = WkT + (size_t)C * C;
    ushort_t* WoT  = WvT + (size_t)C * C;
    ushort_t* qraw = WoT + (size_t)C * C;                         // 3 x 16 MB
    ushort_t* kraw = qraw + (size_t)L * C;
    ushort_t* vraw = kraw + (size_t)L * C;
    ushort_t* aout = vraw + (size_t)L * C;                        // 16 MB
    float* rkArr   = (float*)(aout + (size_t)L * C);              // 32 KB
    float* outp = (float*)d_out;

    cvt_kernel<<<(L * C / 8 + 255) / 256, 256, 0, stream>>>(x, xbf, L * C / 8);
    transpose4_kernel<<<dim3(32, 32, 4), 256, 0, stream>>>(Wq, Wk, Wv, Wo,
                                                           WqT, WkT, WvT, WoT);
    gemm_qkv_kernel<<<dim3(L / 256, C / 128, 3), 256, 0, stream>>>(
        xbf, WqT, WkT, WvT, bq, bk, bv, qraw, kraw, vraw);
    rownorm_k_kernel<<<L / 4, 256, 0, stream>>>(kraw, rkArr);
    attn_kernel<<<L / 4, 256, 0, stream>>>(qraw, kraw, vraw, qn_w, kn_w, eb,
                                           rkArr, aout);
    gemm_o_kernel<<<dim3(L / 256, C / 128), 256, 0, stream>>>(aout, WoT, bo, outp);
}